// Round 6
// baseline (233.273 us; speedup 1.0000x reference)
//
#include <hip/hip_runtime.h>

#define NB 32
#define NP 192
#define DM 48          // max_dur
#define ND 80          // DMEL
#define NH 64          // H
#define NT (NP*DM)     // 9216
#define NBP (NB*NP)    // 6144
#define NSG (NBP/16)   // 384 blocks of 16 sequences
#define NR (NB*NT)     // 294912 mel rows total

typedef _Float16 half8 __attribute__((ext_vector_type(8)));
typedef float f32x4 __attribute__((ext_vector_type(4)));

// workspace layout (bytes)
#define WS_STARTS 0                        // 6144 ints
#define WS_WIH   32768                     // 36864 B
#define WS_WHH   (32768 + 36864)           // 24576 B
#define WS_WIHB  (32768 + 36864 + 24576)   // 36864 B
#define WS_XG    (256*1024)                // 294912 x 96 f16 = 56.6 MB

__device__ __forceinline__ float sigm(float x){ return 1.0f/(1.0f + __expf(-x)); }
__device__ __forceinline__ float tanh_f(float x){ return 1.0f - 2.0f/(1.0f + __expf(2.0f*x)); }

__device__ __forceinline__ unsigned packh2(float a, float b){
    unsigned short ua = __builtin_bit_cast(unsigned short, (_Float16)a);
    unsigned short ub = __builtin_bit_cast(unsigned short, (_Float16)b);
    return (unsigned)ua | ((unsigned)ub << 16);
}

struct Aff { float a0,c0,a1,c1; };
__device__ __forceinline__ Aff make_aff(const float* cw, const float* cb, const float* bg,
                                        const float* bb, const float* bm, const float* bv){
    float s0 = bg[0]*rsqrtf(bv[0]+1e-5f);
    float s1 = bg[1]*rsqrtf(bv[1]+1e-5f);
    Aff A;
    A.a0 = cw[0]*s0; A.c0 = (cb[0]-bm[0])*s0 + bb[0];
    A.a1 = cw[1]*s1; A.c1 = (cb[1]-bm[1])*s1 + bb[1];
    return A;
}
__device__ __forceinline__ float aff(float x, const Aff A){
    float y = fmaxf(fmaf(A.a0, x, A.c0), 0.0f);
    return fmaxf(fmaf(A.a1, y, A.c1), 0.0f);
}

// lgkm-only fence + raw barrier: does NOT drain vmcnt (prefetch stays in flight)
__device__ __forceinline__ void lds_barrier(){
    asm volatile("s_waitcnt lgkmcnt(0)" ::: "memory");
    __builtin_amdgcn_s_barrier();
    asm volatile("" ::: "memory");
}

// ---------------- K_pre: starts-scan + weight frag prep + affined f16 grid --
// blocks [0,32): exclusive cumsum of durations
// blocks [32,224): f16 MFMA A-fragment layout for Wih_f, Whh_f, Wih_b
// blocks [224+): xg[R][96] = f16(aff(mels[R][k])), k>=80 zero-padded
__global__ __launch_bounds__(256) void k_pre(
        const int* __restrict__ dur, int* __restrict__ starts,
        const float* __restrict__ Wih, const float* __restrict__ Whh,
        const float* __restrict__ Wihb,
        unsigned short* __restrict__ wih16, unsigned short* __restrict__ whh16,
        unsigned short* __restrict__ wihb16,
        const float* __restrict__ mels, unsigned short* __restrict__ xg,
        const float* __restrict__ cw, const float* __restrict__ cb,
        const float* __restrict__ bg, const float* __restrict__ bb,
        const float* __restrict__ bm, const float* __restrict__ bv){
    int blk = blockIdx.x, tid = threadIdx.x;
    if (blk < NB){
        __shared__ int s[NP];
        int d = 0;
        if (tid < NP){ d = dur[blk*NP + tid]; s[tid] = d; }
        __syncthreads();
        #pragma unroll
        for (int off = 1; off < NP; off <<= 1){
            int v = (tid >= off && tid < NP) ? s[tid - off] : 0;
            __syncthreads();
            if (tid < NP) s[tid] += v;
            __syncthreads();
        }
        if (tid < NP) starts[blk*NP + tid] = s[tid] - d;
        return;
    }
    if (blk < NB + 192){
        int idx = (blk - NB)*256 + tid;
        if (idx < 12*3*64*8){
            int i = idx & 7, l = (idx>>3) & 63, ks = (idx>>9) % 3, f = idx / 1536;
            int j = (f>>2)*64 + (f&3)*16 + (l&15);
            int k = ks*32 + (l>>4)*8 + i;
            float v = (k < ND) ? Wih[j*ND + k] : 0.0f;
            wih16[idx] = __builtin_bit_cast(unsigned short, (_Float16)v);
            return;
        }
        int idx2 = idx - 12*3*64*8;
        if (idx2 < 12*2*64*8){
            int i = idx2 & 7, l = (idx2>>3) & 63, ks = (idx2>>9) & 1, f = idx2 / 1024;
            int j = (f>>2)*64 + (f&3)*16 + (l&15);
            int k = ks*32 + (l>>4)*8 + i;
            whh16[idx2] = __builtin_bit_cast(unsigned short, (_Float16)Whh[j*NH + k]);
            return;
        }
        int idx3 = idx2 - 12*2*64*8;
        if (idx3 < 12*3*64*8){
            int i = idx3 & 7, l = (idx3>>3) & 63, ks = (idx3>>9) % 3, f = idx3 / 1536;
            int j = (f>>2)*64 + (f&3)*16 + (l&15);
            int k = ks*32 + (l>>4)*8 + i;
            float v = (k < ND) ? Wihb[j*ND + k] : 0.0f;
            wihb16[idx3] = __builtin_bit_cast(unsigned short, (_Float16)v);
        }
        return;
    }
    // affined f16 grid: unit u -> (row R = u/12, k-block kb = u%12)
    Aff A = make_aff(cw,cb,bg,bb,bm,bv);
    int u0 = (blk - (NB+192))*256 + tid;
    int stride = (gridDim.x - (NB+192))*256;
    for (int u = u0; u < NR*12; u += stride){
        int R = u / 12, kb = u % 12, k0 = kb*8;
        uint4 P;
        if (k0 < ND){
            const float* p = mels + (size_t)R*ND + k0;
            float4 a = *(const float4*)p;
            float4 b4 = *(const float4*)(p + 4);
            float y0=aff(a.x,A),  y1=aff(a.y,A),  y2=aff(a.z,A),  y3=aff(a.w,A);
            float y4=aff(b4.x,A), y5=aff(b4.y,A), y6=aff(b4.z,A), y7=aff(b4.w,A);
            P = uint4{packh2(y0,y1), packh2(y2,y3), packh2(y4,y5), packh2(y6,y7)};
        } else {
            P = uint4{0u,0u,0u,0u};
        }
        *(uint4*)(xg + (size_t)R*96 + k0) = P;
    }
}

// ---------------- K_fused: gi MFMA + GRU recurrence + bwd epilogue ----------
// Block: 16 seqs, 4 waves (j-split). x comes pre-affined/pre-packed from xg:
// staging = 1 uint4 load (prefetched 2 steps ahead) + 1 LDS write. h kept f16.
// 15 MFMA/step/wave (9 gi + 6 gh). 1 raw lgkm barrier per step.
__global__ __launch_bounds__(256, 2) void k_fused(
        const unsigned short* __restrict__ xg,
        const int* __restrict__ starts,
        const int* __restrict__ dur,
        const unsigned short* __restrict__ wih16,
        const unsigned short* __restrict__ whh16,
        const unsigned short* __restrict__ wihb16,
        const float* __restrict__ bih,  const float* __restrict__ bhh,
        const float* __restrict__ bihb, const float* __restrict__ bhhb,
        float* __restrict__ out){
    __shared__ alignas(16) uint4 xf[3*192];            // 9216 B, conflict-free
    __shared__ alignas(16) uint4 xlast[192];           // 3072 B
    __shared__ alignas(16) unsigned short hh2[2*1152]; // 2 buf x 16 seq x 72

    int sg  = blockIdx.x;
    int tid = threadIdx.x;
    int w = tid >> 6, l = tid & 63;
    int sc = l & 15, g4 = l >> 4;

    // A fragments
    half8 Af[3][3], Ah[3][2];
    #pragma unroll
    for (int gt = 0; gt < 3; ++gt){
        #pragma unroll
        for (int ks = 0; ks < 3; ++ks)
            Af[gt][ks] = *(const half8*)(wih16 + (size_t)(((gt*4+w)*3 + ks)*64 + l)*8);
        #pragma unroll
        for (int ks = 0; ks < 2; ++ks)
            Ah[gt][ks] = *(const half8*)(whh16 + (size_t)(((gt*4+w)*2 + ks)*64 + l)*8);
    }
    f32x4 bi[3], bh[3];
    #pragma unroll
    for (int gt = 0; gt < 3; ++gt){
        float4 t4 = *(const float4*)(bih + gt*64 + w*16 + g4*4);
        bi[gt][0]=t4.x; bi[gt][1]=t4.y; bi[gt][2]=t4.z; bi[gt][3]=t4.w;
        float4 u4 = *(const float4*)(bhh + gt*64 + w*16 + g4*4);
        bh[gt][0]=u4.x; bh[gt][1]=u4.y; bh[gt][2]=u4.z; bh[gt][3]=u4.w;
    }
    int dl_g = dur[sg*16 + sc];

    // staging role: thread tid<192 owns (ks_s = tid/64, lane ls = tid&63)
    //   -> the 8 f16 at k0 = ks_s*32 + (ls>>4)*8 of seq (ls&15)
    bool stg = (tid < 192);
    int ks_s = tid >> 6, ls = tid & 63;
    int scs = ls & 15, g4s = ls >> 4;
    int k0 = ks_s*32 + g4s*8;
    int st_s = 0, d_s = -1;
    if (stg){ st_s = starts[sg*16 + scs]; d_s = dur[sg*16 + scs]; }
    const unsigned short* xgb = xg + (size_t)(sg/12)*NT*96;

    auto ldx = [&](int t) -> uint4 {
        int r = st_s + t; r = (r < NT-1) ? r : (NT-1);
        return *(const uint4*)(xgb + (size_t)r*96 + k0);
    };

    // ---- prologue: zero h buf0; stage x(0); preload x(1)
    for (int i = tid; i < 144; i += 256)
        ((uint4*)hh2)[i] = uint4{0u,0u,0u,0u};
    uint4 Pa = {0u,0u,0u,0u}, Pb = {0u,0u,0u,0u};
    if (stg){
        Pa = ldx(0);
        xf[tid] = Pa;
        if (0 == d_s - 1) xlast[tid] = Pa;
        Pa = ldx(1);
    }
    float h[4] = {0.f,0.f,0.f,0.f};
    lds_barrier();

#define MFMA(a,b,c) __builtin_amdgcn_mfma_f32_16x16x32_f16(a,b,c,0,0,0)
#define GSTEP(K, PC, PN)                                                              \
{                                                                                     \
    const int PR = (K) % 3, PW = ((K)+1) % 3, HB = (K) & 1;                           \
    const int t = tb + (K);                                                           \
    half8 X0  = *(const half8*)&xf[PR*192 +   0 + l];                                 \
    half8 X1  = *(const half8*)&xf[PR*192 +  64 + l];                                 \
    half8 X2  = *(const half8*)&xf[PR*192 + 128 + l];                                 \
    half8 Hh0 = *(const half8*)&hh2[HB*1152 + sc*72 +  0 + g4*8];                     \
    half8 Hh1 = *(const half8*)&hh2[HB*1152 + sc*72 + 32 + g4*8];                     \
    if (stg && (t+1 < DM)){                                                           \
        xf[PW*192 + tid] = PC;                                                        \
        if ((t+1) == d_s - 1) xlast[tid] = PC;                                        \
    }                                                                                 \
    if (stg && (t+2 < DM)) PN = ldx(t+2);                                             \
    f32x4 ga0 = bi[0], ga1 = bi[1], ga2 = bi[2];                                      \
    f32x4 ha0 = bh[0], ha1 = bh[1], ha2 = bh[2];                                      \
    ha0 = MFMA(Ah[0][0], Hh0, ha0); ha1 = MFMA(Ah[1][0], Hh0, ha1);                   \
    ha2 = MFMA(Ah[2][0], Hh0, ha2);                                                   \
    ga0 = MFMA(Af[0][0], X0, ga0);  ga1 = MFMA(Af[1][0], X0, ga1);                    \
    ga2 = MFMA(Af[2][0], X0, ga2);                                                    \
    ha0 = MFMA(Ah[0][1], Hh1, ha0); ha1 = MFMA(Ah[1][1], Hh1, ha1);                   \
    ha2 = MFMA(Ah[2][1], Hh1, ha2);                                                   \
    ga0 = MFMA(Af[0][1], X1, ga0);  ga1 = MFMA(Af[1][1], X1, ga1);                    \
    ga2 = MFMA(Af[2][1], X1, ga2);                                                    \
    ga0 = MFMA(Af[0][2], X2, ga0);  ga1 = MFMA(Af[1][2], X2, ga1);                    \
    ga2 = MFMA(Af[2][2], X2, ga2);                                                    \
    _Pragma("unroll")                                                                 \
    for (int r = 0; r < 4; ++r){                                                      \
        float rr = sigm(ga0[r] + ha0[r]);                                             \
        float zz = sigm(ga1[r] + ha1[r]);                                             \
        float nn = tanh_f(ga2[r] + rr*ha2[r]);                                        \
        float hn2 = (1.0f - zz)*nn + zz*h[r];                                         \
        h[r] = (t < dl_g) ? hn2 : h[r];                                               \
    }                                                                                 \
    *(uint2*)&hh2[(HB^1)*1152 + sc*72 + w*16 + g4*4] =                                \
        uint2{packh2(h[0],h[1]), packh2(h[2],h[3])};                                  \
    lds_barrier();                                                                    \
}

    for (int tb = 0; tb < DM; tb += 6){
        GSTEP(0, Pa, Pb)
        GSTEP(1, Pb, Pa)
        GSTEP(2, Pa, Pb)
        GSTEP(3, Pb, Pa)
        GSTEP(4, Pa, Pb)
        GSTEP(5, Pb, Pa)
    }
#undef GSTEP

    // ---- forward output
    float mk = (dl_g > 0) ? 1.0f : 0.0f;
    {
        float4 o4 = {h[0]*mk, h[1]*mk, h[2]*mk, h[3]*mk};
        *(float4*)(out + ((size_t)sg*16 + sc)*(2*NH) + w*16 + g4*4) = o4;
    }

    // ---- backward GRU single step from h=0 on xlast (frag-ready f16)
    half8 Afb[3][3];
    #pragma unroll
    for (int gt = 0; gt < 3; ++gt)
        #pragma unroll
        for (int ks = 0; ks < 3; ++ks)
            Afb[gt][ks] = *(const half8*)(wihb16 + (size_t)(((gt*4+w)*3 + ks)*64 + l)*8);
    f32x4 ab0, ab1, ab2;
    {
        float4 t0 = *(const float4*)(bihb + 0*64 + w*16 + g4*4);
        float4 t1 = *(const float4*)(bihb + 1*64 + w*16 + g4*4);
        float4 t2 = *(const float4*)(bihb + 2*64 + w*16 + g4*4);
        ab0[0]=t0.x; ab0[1]=t0.y; ab0[2]=t0.z; ab0[3]=t0.w;
        ab1[0]=t1.x; ab1[1]=t1.y; ab1[2]=t1.z; ab1[3]=t1.w;
        ab2[0]=t2.x; ab2[1]=t2.y; ab2[2]=t2.z; ab2[3]=t2.w;
    }
    #pragma unroll
    for (int ks = 0; ks < 3; ++ks){
        half8 Bx = *(const half8*)&xlast[ks*64 + l];
        ab0 = MFMA(Afb[0][ks], Bx, ab0);
        ab1 = MFMA(Afb[1][ks], Bx, ab1);
        ab2 = MFMA(Afb[2][ks], Bx, ab2);
    }
    {
        float4 p0 = *(const float4*)(bhhb + 0*64 + w*16 + g4*4);
        float4 p1 = *(const float4*)(bhhb + 1*64 + w*16 + g4*4);
        float4 p2 = *(const float4*)(bhhb + 2*64 + w*16 + g4*4);
        float pr0[4] = {p0.x,p0.y,p0.z,p0.w};
        float pr1[4] = {p1.x,p1.y,p1.z,p1.w};
        float pr2[4] = {p2.x,p2.y,p2.z,p2.w};
        float ho[4];
        #pragma unroll
        for (int r = 0; r < 4; ++r){
            float rr = sigm(ab0[r] + pr0[r]);
            float zz = sigm(ab1[r] + pr1[r]);
            float nn = tanh_f(ab2[r] + rr*pr2[r]);
            ho[r] = (1.0f - zz)*nn * mk;
        }
        float4 o4 = {ho[0], ho[1], ho[2], ho[3]};
        *(float4*)(out + ((size_t)sg*16 + sc)*(2*NH) + NH + w*16 + g4*4) = o4;
    }
#undef MFMA
}

extern "C" void kernel_launch(void* const* d_in, const int* in_sizes, int n_in,
                              void* d_out, int out_size, void* d_ws, size_t ws_size,
                              hipStream_t stream){
    const float* mels = (const float*)d_in[0];
    const int*   dur  = (const int*)d_in[1];
    const float* cw = (const float*)d_in[3];
    const float* cb = (const float*)d_in[4];
    const float* bg = (const float*)d_in[5];
    const float* bb = (const float*)d_in[6];
    const float* bm = (const float*)d_in[7];
    const float* bv = (const float*)d_in[8];
    const float* Wihf = (const float*)d_in[9];
    const float* Whhf = (const float*)d_in[10];
    const float* bihf = (const float*)d_in[11];
    const float* bhhf = (const float*)d_in[12];
    const float* Wihb = (const float*)d_in[13];
    // d_in[14] = W_hh_b — unused (h0 = 0 => gh = bhh_b)
    const float* bihb = (const float*)d_in[15];
    const float* bhhb = (const float*)d_in[16];
    float* out = (float*)d_out;

    int*            starts = (int*)((char*)d_ws + WS_STARTS);
    unsigned short* wih16  = (unsigned short*)((char*)d_ws + WS_WIH);
    unsigned short* whh16  = (unsigned short*)((char*)d_ws + WS_WHH);
    unsigned short* wihb16 = (unsigned short*)((char*)d_ws + WS_WIHB);
    unsigned short* xg     = (unsigned short*)((char*)d_ws + WS_XG);

    k_pre<<<NB + 192 + 1024, 256, 0, stream>>>(dur, starts, Wihf, Whhf, Wihb,
                                               wih16, whh16, wihb16, mels, xg,
                                               cw, cb, bg, bb, bm, bv);
    k_fused<<<NSG, 256, 0, stream>>>(xg, starts, dur, wih16, whh16, wihb16,
                                     bihf, bhhf, bihb, bhhb, out);
}